// Round 1
// baseline (614.535 us; speedup 1.0000x reference)
//
#include <hip/hip_runtime.h>

#define CHW 262144   // C*H*W = 256*32*32
#define HWD 1024     // H*W

// workspace layout (float offsets)
static const unsigned OFF_A    = 0;        // ||z_n||^2          [8192]
static const unsigned OFF_B    = 8192;     // ||e_k||^2          [8192]
static const unsigned OFF_EMBT = 16384;    // emb^T [256][8192]  [2097152]
static const unsigned OFF_PD   = 2113536;  // partial dists [8192][64]
static const unsigned OFF_PK   = 2637824;  // partial ks    [8192][64] (int)
static const unsigned OFF_IDX  = 3162112;  // idx (int)     [8192]
static const unsigned OFF_NCS0 = 3170304;  // pre-norm new_cs [8192]
static const unsigned OFF_CNT  = 3178496;  // counts (int, ZEROED) [8192]
static const unsigned OFF_DW   = 3186688;  // dw (ZEROED) [2097152]
static const unsigned OFF_SCAL = 5283840;  // [0]=loss_sum [1]=n_sum (ZEROED)

// ---- ||z_n||^2 : zf[n][c] = z[b, c, hw], n = b*1024 + hw ----
__global__ __launch_bounds__(256) void k_sqz(const float* __restrict__ z, float* __restrict__ asq) {
    int n = blockIdx.x * 256 + threadIdx.x;
    const float* p = z + (size_t)(n >> 10) * CHW + (n & 1023);
    float s = 0.f;
    #pragma unroll 8
    for (int c = 0; c < 256; ++c) { float v = p[(size_t)c << 10]; s = fmaf(v, v, s); }
    asq[n] = s;
}

// ---- ||e_k||^2 : one wave per row ----
__global__ __launch_bounds__(256) void k_sqe(const float* __restrict__ emb, float* __restrict__ bsq) {
    int w = blockIdx.x * 4 + (threadIdx.x >> 6);
    int lane = threadIdx.x & 63;
    float4 v = *(const float4*)(emb + (size_t)w * 256 + lane * 4);
    float s = v.x * v.x;
    s = fmaf(v.y, v.y, s);
    s = fmaf(v.z, v.z, s);
    s = fmaf(v.w, v.w, s);
    #pragma unroll
    for (int m = 1; m < 64; m <<= 1) s += __shfl_xor(s, m, 64);
    if (lane == 0) bsq[w] = s;
}

// ---- transpose emb [8192][256] -> embT [256][8192] ----
__global__ __launch_bounds__(256) void k_tr(const float* __restrict__ emb, float* __restrict__ embT) {
    __shared__ float s[64][65];
    int k0 = blockIdx.x * 64, c0 = blockIdx.y * 64;
    int tid = threadIdx.x;
    #pragma unroll
    for (int i = 0; i < 16; ++i) {
        int e = tid + i * 256;
        int c = e & 63, k = e >> 6;
        s[k][c] = emb[(size_t)(k0 + k) * 256 + c0 + c];
    }
    __syncthreads();
    #pragma unroll
    for (int i = 0; i < 16; ++i) {
        int e = tid + i * 256;
        int k = e & 63, c = e >> 6;
        embT[(size_t)(c0 + c) * 8192 + k0 + k] = s[k][c];
    }
}

// ---- main: 128x128 tile fp32 matmul + fused (a+b-2S) argmin partials ----
__global__ __launch_bounds__(256) void k_main(const float* __restrict__ z, const float* __restrict__ embT,
        const float* __restrict__ asq, const float* __restrict__ bsq,
        float* __restrict__ pd, int* __restrict__ pk) {
    __shared__ float As[32][132];
    __shared__ float Bs[32][132];
    const int kt = blockIdx.x, nt = blockIdx.y;
    const int n0 = nt * 128, k0 = kt * 128;
    const int b = n0 >> 10, hw0 = n0 & 1023;
    const float* Ap = z + (size_t)b * CHW + hw0;       // A[c][n] = Ap[c*1024 + n]
    const float* Bp = embT + k0;                       // B[c][k] = Bp[c*8192 + k]
    const int tid = threadIdx.x;
    const int tx = tid & 15, ty = tid >> 4;
    float acc[8][8];
    #pragma unroll
    for (int i = 0; i < 8; ++i)
        #pragma unroll
        for (int j = 0; j < 8; ++j) acc[i][j] = 0.f;

    for (int cb = 0; cb < 8; ++cb) {
        const int c0 = cb * 32;
        #pragma unroll
        for (int i = 0; i < 4; ++i) {
            int e = tid + i * 256;
            int c = e >> 5, x4 = (e & 31) << 2;
            *(float4*)(&As[c][x4]) = *(const float4*)(Ap + (size_t)(c0 + c) * HWD + x4);
            *(float4*)(&Bs[c][x4]) = *(const float4*)(Bp + (size_t)(c0 + c) * 8192 + x4);
        }
        __syncthreads();
        #pragma unroll 4
        for (int cc = 0; cc < 32; ++cc) {
            float av[8], bv[8];
            *(float4*)(av)     = *(const float4*)(&As[cc][ty * 4]);
            *(float4*)(av + 4) = *(const float4*)(&As[cc][64 + ty * 4]);
            *(float4*)(bv)     = *(const float4*)(&Bs[cc][tx * 4]);
            *(float4*)(bv + 4) = *(const float4*)(&Bs[cc][64 + tx * 4]);
            #pragma unroll
            for (int i = 0; i < 8; ++i)
                #pragma unroll
                for (int j = 0; j < 8; ++j)
                    acc[i][j] = fmaf(av[i], bv[j], acc[i][j]);
        }
        __syncthreads();
    }

    // epilogue: d = fl(fl(a+b) - 2*S), argmin (strict <, ascending k)
    int rown[8], colk[8];
    #pragma unroll
    for (int i = 0; i < 4; ++i) { rown[i] = n0 + ty * 4 + i; rown[i + 4] = n0 + 64 + ty * 4 + i; }
    #pragma unroll
    for (int j = 0; j < 4; ++j) { colk[j] = k0 + tx * 4 + j; colk[j + 4] = k0 + 64 + tx * 4 + j; }
    float bvv[8];
    #pragma unroll
    for (int j = 0; j < 8; ++j) bvv[j] = bsq[colk[j]];
    #pragma unroll
    for (int i = 0; i < 8; ++i) {
        float ai = asq[rown[i]];
        float dmin = 3.4e38f;
        int kmin = 0;
        #pragma unroll
        for (int j = 0; j < 8; ++j) {           // colk ascending within thread
            float s = ai + bvv[j];
            float dd = s - 2.0f * acc[i][j];    // == fma(-2,acc,s); 2*acc exact
            if (dd < dmin) { dmin = dd; kmin = colk[j]; }
        }
        #pragma unroll
        for (int m = 1; m < 16; m <<= 1) {      // reduce across the 16 tx lanes
            float od = __shfl_xor(dmin, m, 64);
            int   ok = __shfl_xor(kmin, m, 64);
            if (od < dmin || (od == dmin && ok < kmin)) { dmin = od; kmin = ok; }
        }
        if (tx == 0) {
            pd[(size_t)rown[i] * 64 + kt] = dmin;
            pk[(size_t)rown[i] * 64 + kt] = kmin;
        }
    }
}

// ---- reduce 64 tile-partials per n, write idx, histogram ----
__global__ __launch_bounds__(256) void k_red(const float* __restrict__ pd, const int* __restrict__ pk,
        int* __restrict__ idxw, float* __restrict__ out_idx, int* __restrict__ cnt) {
    int n = blockIdx.x * 4 + (threadIdx.x >> 6);
    int lane = threadIdx.x & 63;
    float d = pd[(size_t)n * 64 + lane];
    int k = pk[(size_t)n * 64 + lane];
    #pragma unroll
    for (int m = 1; m < 64; m <<= 1) {
        float od = __shfl_xor(d, m, 64);
        int   ok = __shfl_xor(k, m, 64);
        if (od < d || (od == d && ok < k)) { d = od; k = ok; }
    }
    if (lane == 0) {
        idxw[n] = k;
        out_idx[n] = (float)k;
        atomicAdd(cnt + k, 1);
    }
}

// ---- z_q gather + straight-through write + loss partial + dw scatter ----
__global__ __launch_bounds__(256) void k_zq(const float* __restrict__ z, const float* __restrict__ emb,
        const int* __restrict__ idxw, float* __restrict__ out_zq,
        float* __restrict__ dw, float* __restrict__ scal) {
    int n0 = blockIdx.x * 64, c00 = blockIdx.y * 64;
    int lane = threadIdx.x & 63, g = threadIdx.x >> 6;
    int n = n0 + lane;
    int b = n >> 10, hw = n & 1023;
    int idxn = idxw[n];
    const float* zr = z + (size_t)b * CHW + hw;
    const float* er = emb + (size_t)idxn * 256;
    float* dwr = dw + (size_t)idxn * 256;
    float* oz = out_zq + (size_t)b * CHW + hw;
    float ls = 0.f;
    #pragma unroll
    for (int j = 0; j < 16; ++j) {
        int c = c00 + g * 16 + j;
        float zp = zr[(size_t)c << 10];
        float zq = er[c];
        float dif = zq - zp;
        oz[(size_t)c << 10] = zp + dif;     // zp + sg(z_q - zp), literally
        ls = fmaf(dif, dif, ls);
        atomicAdd(dwr + c, zp);             // dw[idx][c] += zf[n][c]
    }
    #pragma unroll
    for (int m = 1; m < 64; m <<= 1) ls += __shfl_xor(ls, m, 64);
    __shared__ float red[4];
    if (lane == 0) red[g] = ls;
    __syncthreads();
    if (threadIdx.x == 0) atomicAdd(scal, red[0] + red[1] + red[2] + red[3]);
}

// ---- new_cs pre-normalization + n = sum ----
__global__ __launch_bounds__(256) void k_ncs(const float* __restrict__ cs, const int* __restrict__ cnt,
        float* __restrict__ ncs0, float* __restrict__ scal) {
    int k = blockIdx.x * 256 + threadIdx.x;
    const float C1 = (float)(1.0 - 0.99);
    float v = cs[k] * 0.99f + C1 * (float)cnt[k];
    ncs0[k] = v;
    float s = v;
    #pragma unroll
    for (int m = 1; m < 64; m <<= 1) s += __shfl_xor(s, m, 64);
    __shared__ float red[4];
    if ((threadIdx.x & 63) == 0) red[threadIdx.x >> 6] = s;
    __syncthreads();
    if (threadIdx.x == 0) atomicAdd(scal + 1, red[0] + red[1] + red[2] + red[3]);
}

// ---- finalize: new_cs, new_ema_w, new_embedding, loss ----
__global__ __launch_bounds__(256) void k_fin(const float* __restrict__ ncs0, const float* __restrict__ ema,
        const float* __restrict__ dw, const float* __restrict__ scal,
        float* __restrict__ out_ncs, float* __restrict__ out_ema,
        float* __restrict__ out_emb, float* __restrict__ out_loss) {
    int k = blockIdx.x * 4 + (threadIdx.x >> 6);
    int lane = threadIdx.x & 63;
    float nsum = scal[1];
    const float KEPS = (float)(8192 * 1e-5);
    float ncs = (ncs0[k] + 1e-5f) / (nsum + KEPS) * nsum;
    if (lane == 0) out_ncs[k] = ncs;
    const float C1 = (float)(1.0 - 0.99);
    size_t base = (size_t)k * 256 + lane * 4;
    float4 e4 = *(const float4*)(ema + base);
    float4 d4 = *(const float4*)(dw + base);
    float r0 = e4.x * 0.99f + C1 * d4.x;
    float r1 = e4.y * 0.99f + C1 * d4.y;
    float r2 = e4.z * 0.99f + C1 * d4.z;
    float r3 = e4.w * 0.99f + C1 * d4.w;
    // out offsets are odd -> scalar stores (float4 would be misaligned)
    out_ema[base + 0] = r0; out_ema[base + 1] = r1; out_ema[base + 2] = r2; out_ema[base + 3] = r3;
    out_emb[base + 0] = r0 / ncs; out_emb[base + 1] = r1 / ncs;
    out_emb[base + 2] = r2 / ncs; out_emb[base + 3] = r3 / ncs;
    if (blockIdx.x == 0 && threadIdx.x == 0) {
        float m = scal[0] * (1.0f / 2097152.0f);   // /2^21 exact
        out_loss[0] = m + 0.25f * m;               // mean + BETA*mean
    }
}

extern "C" void kernel_launch(void* const* d_in, const int* in_sizes, int n_in,
                              void* d_out, int out_size, void* d_ws, size_t ws_size,
                              hipStream_t stream) {
    const float* z   = (const float*)d_in[0];
    const float* emb = (const float*)d_in[1];
    const float* cs  = (const float*)d_in[2];
    const float* ema = (const float*)d_in[3];
    float* out = (float*)d_out;
    float* wsf = (float*)d_ws;

    float* asq  = wsf + OFF_A;
    float* bsq  = wsf + OFF_B;
    float* embT = wsf + OFF_EMBT;
    float* pd   = wsf + OFF_PD;
    int*   pk   = (int*)(wsf + OFF_PK);
    int*   idxw = (int*)(wsf + OFF_IDX);
    float* ncs0 = wsf + OFF_NCS0;
    int*   cnt  = (int*)(wsf + OFF_CNT);
    float* dw   = wsf + OFF_DW;
    float* scal = wsf + OFF_SCAL;

    float* out_zq   = out;                 // [2097152]
    float* out_loss = out + 2097152;       // [1]
    float* out_idx  = out + 2097153;       // [8192] (as float)
    float* out_ncs  = out + 2105345;       // [8192]
    float* out_ema  = out + 2113537;       // [2097152]
    float* out_emb  = out + 4210689;       // [2097152]

    // zero counts + dw + scalars (contiguous region)
    hipMemsetAsync(wsf + OFF_CNT, 0, (size_t)(8192 + 2097152 + 2) * sizeof(float), stream);

    k_sqz<<<32, 256, 0, stream>>>(z, asq);
    k_sqe<<<2048, 256, 0, stream>>>(emb, bsq);
    k_tr<<<dim3(128, 4), 256, 0, stream>>>(emb, embT);
    k_main<<<dim3(64, 64), 256, 0, stream>>>(z, embT, asq, bsq, pd, pk);
    k_red<<<2048, 256, 0, stream>>>(pd, pk, idxw, out_idx, cnt);
    k_zq<<<dim3(128, 4), 256, 0, stream>>>(z, emb, idxw, out_zq, dw, scal);
    k_ncs<<<32, 256, 0, stream>>>(cs, cnt, ncs0, scal);
    k_fin<<<2048, 256, 0, stream>>>(ncs0, ema, dw, scal, out_ncs, out_ema, out_emb, out_loss);
}

// Round 2
// 385.427 us; speedup vs baseline: 1.5944x; 1.5944x over previous
//
#include <hip/hip_runtime.h>

#define CHW 262144   // C*H*W = 256*32*32
#define HWD 1024     // H*W

typedef _Float16 v8h __attribute__((ext_vector_type(8)));
typedef _Float16 v4h __attribute__((ext_vector_type(4)));
typedef float    v4f __attribute__((ext_vector_type(4)));

// workspace layout (float offsets)
static const unsigned OFF_ASQ  = 0;        // ||z_n||^2 [8192]
static const unsigned OFF_BSQ  = 8192;     // ||e_k||^2 [8192]
static const unsigned OFF_IDX  = 16384;    // idx (int) [8192]
static const unsigned OFF_NCS0 = 24576;    // pre-norm new_cs [8192]
static const unsigned OFF_CNT  = 32768;    // counts (int, ZEROED) [8192]
static const unsigned OFF_SCAL = 40960;    // [0]=loss_sum [1]=n_sum (ZEROED)
static const unsigned OFF_DW   = 49152;    // dw (ZEROED) [2097152]
static const unsigned OFF_BH   = 2146304;  // Bh fp16 [8192*256] (1048576 floats)
static const unsigned OFF_BM   = 3194880;  // Bm fp16 [8192*256]
// end: 4243456 floats = 17.0 MB

#define GLL(g, l) __builtin_amdgcn_global_load_lds( \
    (const __attribute__((address_space(1))) void*)(g), \
    (__attribute__((address_space(3))) void*)(l), 16, 0, 0)

// ---- ||z_n||^2 ----
__global__ __launch_bounds__(256) void k_sqz(const float* __restrict__ z, float* __restrict__ asq) {
    int n = blockIdx.x * 256 + threadIdx.x;
    const float* p = z + (size_t)(n >> 10) * CHW + (n & 1023);
    float s = 0.f;
    #pragma unroll 8
    for (int c = 0; c < 256; ++c) { float v = p[(size_t)c << 10]; s = fmaf(v, v, s); }
    asq[n] = s;
}

// ---- emb -> bsq + fp16 split (e' = e*2^13; m-part scaled by 2^11) ----
__global__ __launch_bounds__(256) void prep_e(const float* __restrict__ emb, float* __restrict__ bsq,
        _Float16* __restrict__ Bh, _Float16* __restrict__ Bm) {
    int w = blockIdx.x * 4 + (threadIdx.x >> 6);
    int lane = threadIdx.x & 63;
    float4 v = *(const float4*)(emb + (size_t)w * 256 + lane * 4);
    float s = v.x * v.x;
    s = fmaf(v.y, v.y, s); s = fmaf(v.z, v.z, s); s = fmaf(v.w, v.w, s);
    #pragma unroll
    for (int m = 1; m < 64; m <<= 1) s += __shfl_xor(s, m, 64);
    if (lane == 0) bsq[w] = s;
    float e0 = v.x * 8192.0f, e1 = v.y * 8192.0f, e2 = v.z * 8192.0f, e3 = v.w * 8192.0f;
    _Float16 h0 = (_Float16)e0, h1 = (_Float16)e1, h2 = (_Float16)e2, h3 = (_Float16)e3;
    v4h hv = {h0, h1, h2, h3};
    v4h mv = {(_Float16)((e0 - (float)h0) * 2048.0f),
              (_Float16)((e1 - (float)h1) * 2048.0f),
              (_Float16)((e2 - (float)h2) * 2048.0f),
              (_Float16)((e3 - (float)h3) * 2048.0f)};
    *(v4h*)(Bh + (size_t)w * 256 + lane * 4) = hv;
    *(v4h*)(Bm + (size_t)w * 256 + lane * 4) = mv;
}

// ---- z [b][c][hw] -> Ah/Am [n][c] fp16 (transpose + split) ----
__global__ __launch_bounds__(256) void prep_z(const float* __restrict__ z,
        _Float16* __restrict__ Ah, _Float16* __restrict__ Am) {
    __shared__ float s[64][65];
    int hw0 = (blockIdx.x & 15) * 64;
    int c0  = ((blockIdx.x >> 4) & 3) * 64;
    int b   = blockIdx.x >> 6;
    int t = threadIdx.x;
    #pragma unroll
    for (int ii = 0; ii < 16; ++ii) {
        int e = t + ii * 256;
        int c = e >> 6, x = e & 63;
        s[c][x] = z[(size_t)b * CHW + (size_t)(c0 + c) * HWD + hw0 + x];
    }
    __syncthreads();
    int n = t & 63, cseg = (t >> 6) * 16;
    _Float16 hbuf[16], mbuf[16];
    #pragma unroll
    for (int j = 0; j < 16; ++j) {
        float v = s[cseg + j][n];
        _Float16 h = (_Float16)v;
        float r = v - (float)h;
        hbuf[j] = h;
        mbuf[j] = (_Float16)(r * 2048.0f);
    }
    size_t off = ((size_t)b * 1024 + hw0 + n) * 256 + c0 + cseg;
    *(v8h*)(Ah + off)     = *(v8h*)(hbuf);
    *(v8h*)(Ah + off + 8) = *(v8h*)(hbuf + 8);
    *(v8h*)(Am + off)     = *(v8h*)(mbuf);
    *(v8h*)(Am + off + 8) = *(v8h*)(mbuf + 8);
}

// ---- main: 128x128 MFMA tiles, 3-product fp16x2, fused argmin partials ----
__global__ __launch_bounds__(256, 2) void k_main(
        const _Float16* __restrict__ Ah, const _Float16* __restrict__ Am,
        const _Float16* __restrict__ Bh, const _Float16* __restrict__ Bm,
        const float* __restrict__ asq, const float* __restrict__ bsq,
        unsigned long long* __restrict__ pdk) {
    __shared__ _Float16 lds[16384];  // 32 KB: 4 mats x [128 rows x 32 halves], XOR-swizzled
    const int kt = blockIdx.x, nt = blockIdx.y;
    const int n0 = nt * 128, k0 = kt * 128;
    const int t = threadIdx.x;
    const int lane = t & 63, w = t >> 6;
    const int wrow = w >> 1, wcol = w & 1;
    const int lm = lane & 15, quad = lane >> 4;

    v4f acc1[4][4], acc2[4][4];
    #pragma unroll
    for (int i = 0; i < 4; ++i)
        #pragma unroll
        for (int j = 0; j < 4; ++j) { acc1[i][j] = (v4f){0.f,0.f,0.f,0.f}; acc2[i][j] = (v4f){0.f,0.f,0.f,0.f}; }

    // staging: chunk = q*256 + t; row = chunk>>2; c4 = (chunk&3) ^ ((row>>1)&3)
    const int row0 = t >> 2;
    const int c40 = (t & 3) ^ ((row0 >> 1) & 3);
    const char* gA0 = (const char*)Ah + (size_t)(n0 + row0) * 512 + c40 * 16;
    const char* gAm0 = (const char*)Am + (size_t)(n0 + row0) * 512 + c40 * 16;
    const char* gB0 = (const char*)Bh + (size_t)(k0 + row0) * 512 + c40 * 16;
    const char* gBm0 = (const char*)Bm + (size_t)(k0 + row0) * 512 + c40 * 16;
    _Float16* l0 = lds + t * 8;          // q=0 dest (per-lane 16B)
    _Float16* l1 = lds + 2048 + t * 8;   // q=1 dest

    // frag LDS half-offsets (A rows, B rows share formula)
    int sa[4], sb[4];
    #pragma unroll
    for (int i = 0; i < 4; ++i) {
        int mr = wrow * 64 + i * 16 + lm;
        sa[i] = mr * 32 + ((quad ^ ((mr >> 1) & 3)) * 8);
        int nr = wcol * 64 + i * 16 + lm;
        sb[i] = nr * 32 + ((quad ^ ((nr >> 1) & 3)) * 8);
    }

    for (int cb = 0; cb < 8; ++cb) {
        const size_t co = (size_t)cb * 64;  // 32 c * 2B
        GLL(gA0 + co,          l0);
        GLL(gA0 + co + 32768,  l1);          // +64 rows * 512 B
        GLL(gAm0 + co,         l0 + 4096);
        GLL(gAm0 + co + 32768, l1 + 4096);
        GLL(gB0 + co,          l0 + 8192);
        GLL(gB0 + co + 32768,  l1 + 8192);
        GLL(gBm0 + co,         l0 + 12288);
        GLL(gBm0 + co + 32768, l1 + 12288);
        __syncthreads();

        v8h fa[4], fam[4], fb[4], fbm[4];
        #pragma unroll
        for (int i = 0; i < 4; ++i) {
            fa[i]  = *(const v8h*)(lds + sa[i]);
            fam[i] = *(const v8h*)(lds + 4096 + sa[i]);
            fb[i]  = *(const v8h*)(lds + 8192 + sb[i]);
            fbm[i] = *(const v8h*)(lds + 12288 + sb[i]);
        }
        #pragma unroll
        for (int i = 0; i < 4; ++i)
            #pragma unroll
            for (int j = 0; j < 4; ++j) {
                acc1[i][j] = __builtin_amdgcn_mfma_f32_16x16x32_f16(fa[i], fb[j], acc1[i][j], 0, 0, 0);
                acc2[i][j] = __builtin_amdgcn_mfma_f32_16x16x32_f16(fa[i], fbm[j], acc2[i][j], 0, 0, 0);
                acc2[i][j] = __builtin_amdgcn_mfma_f32_16x16x32_f16(fam[i], fb[j], acc2[i][j], 0, 0, 0);
            }
        __syncthreads();
    }

    // epilogue: d = fl(fl(a+b) - 2*S), S = (acc1 + acc2*2^-11)*2^-13
    float bvv[4];
    #pragma unroll
    for (int j = 0; j < 4; ++j) bvv[j] = bsq[k0 + wcol * 64 + j * 16 + lm];
    #pragma unroll
    for (int i = 0; i < 4; ++i) {
        #pragma unroll
        for (int r = 0; r < 4; ++r) {
            int m = n0 + wrow * 64 + i * 16 + quad * 4 + r;
            float av_ = asq[m];
            unsigned long long best = ~0ull;
            #pragma unroll
            for (int j = 0; j < 4; ++j) {
                float S = fmaf(acc2[i][j][r], 4.8828125e-4f, acc1[i][j][r]) * 1.220703125e-4f;
                float dd = (av_ + bvv[j]) - 2.0f * S;
                int col = k0 + wcol * 64 + j * 16 + lm;
                unsigned long long key = ((unsigned long long)__float_as_uint(dd) << 13) | (unsigned)col;
                best = key < best ? key : best;
            }
            #pragma unroll
            for (int xm = 1; xm < 16; xm <<= 1) {
                unsigned long long o = __shfl_xor(best, xm, 64);
                best = o < best ? o : best;
            }
            if (lm == 0) pdk[(size_t)m * 128 + kt * 2 + wcol] = best;
        }
    }
}

// ---- reduce 128 tile-partials per n, write idx, histogram ----
__global__ __launch_bounds__(256) void k_red(const unsigned long long* __restrict__ pdk,
        int* __restrict__ idxw, float* __restrict__ out_idx, int* __restrict__ cnt) {
    int n = blockIdx.x * 4 + (threadIdx.x >> 6);
    int lane = threadIdx.x & 63;
    unsigned long long a = pdk[(size_t)n * 128 + lane];
    unsigned long long b = pdk[(size_t)n * 128 + 64 + lane];
    unsigned long long v = a < b ? a : b;
    #pragma unroll
    for (int m = 1; m < 64; m <<= 1) {
        unsigned long long o = __shfl_xor(v, m, 64);
        v = o < v ? o : v;
    }
    if (lane == 0) {
        int k = (int)(v & 8191u);
        idxw[n] = k;
        out_idx[n] = (float)k;
        atomicAdd(cnt + k, 1);
    }
}

// ---- z_q gather + straight-through write + loss partial + dw scatter ----
__global__ __launch_bounds__(256) void k_zq(const float* __restrict__ z, const float* __restrict__ emb,
        const int* __restrict__ idxw, float* __restrict__ out_zq,
        float* __restrict__ dw, float* __restrict__ scal) {
    int n0 = blockIdx.x * 64, c00 = blockIdx.y * 64;
    int lane = threadIdx.x & 63, g = threadIdx.x >> 6;
    int n = n0 + lane;
    int b = n >> 10, hw = n & 1023;
    int idxn = idxw[n];
    const float* zr = z + (size_t)b * CHW + hw;
    const float* er = emb + (size_t)idxn * 256;
    float* dwr = dw + (size_t)idxn * 256;
    float* oz = out_zq + (size_t)b * CHW + hw;
    float ls = 0.f;
    #pragma unroll
    for (int j = 0; j < 16; ++j) {
        int c = c00 + g * 16 + j;
        float zp = zr[(size_t)c << 10];
        float zq = er[c];
        float dif = zq - zp;
        oz[(size_t)c << 10] = zp + dif;
        ls = fmaf(dif, dif, ls);
        atomicAdd(dwr + c, zp);
    }
    #pragma unroll
    for (int m = 1; m < 64; m <<= 1) ls += __shfl_xor(ls, m, 64);
    __shared__ float red[4];
    if (lane == 0) red[g] = ls;
    __syncthreads();
    if (threadIdx.x == 0) atomicAdd(scal, red[0] + red[1] + red[2] + red[3]);
}

// ---- new_cs pre-normalization + n = sum ----
__global__ __launch_bounds__(256) void k_ncs(const float* __restrict__ cs, const int* __restrict__ cnt,
        float* __restrict__ ncs0, float* __restrict__ scal) {
    int k = blockIdx.x * 256 + threadIdx.x;
    const float C1 = (float)(1.0 - 0.99);
    float v = cs[k] * 0.99f + C1 * (float)cnt[k];
    ncs0[k] = v;
    float s = v;
    #pragma unroll
    for (int m = 1; m < 64; m <<= 1) s += __shfl_xor(s, m, 64);
    __shared__ float red[4];
    if ((threadIdx.x & 63) == 0) red[threadIdx.x >> 6] = s;
    __syncthreads();
    if (threadIdx.x == 0) atomicAdd(scal + 1, red[0] + red[1] + red[2] + red[3]);
}

// ---- finalize ----
__global__ __launch_bounds__(256) void k_fin(const float* __restrict__ ncs0, const float* __restrict__ ema,
        const float* __restrict__ dw, const float* __restrict__ scal,
        float* __restrict__ out_ncs, float* __restrict__ out_ema,
        float* __restrict__ out_emb, float* __restrict__ out_loss) {
    int k = blockIdx.x * 4 + (threadIdx.x >> 6);
    int lane = threadIdx.x & 63;
    float nsum = scal[1];
    const float KEPS = (float)(8192 * 1e-5);
    float ncs = (ncs0[k] + 1e-5f) / (nsum + KEPS) * nsum;
    if (lane == 0) out_ncs[k] = ncs;
    const float C1 = (float)(1.0 - 0.99);
    size_t base = (size_t)k * 256 + lane * 4;
    float4 e4 = *(const float4*)(ema + base);
    float r0 = e4.x * 0.99f + C1 * dw[base + 0];
    float r1 = e4.y * 0.99f + C1 * dw[base + 1];
    float r2 = e4.z * 0.99f + C1 * dw[base + 2];
    float r3 = e4.w * 0.99f + C1 * dw[base + 3];
    out_ema[base + 0] = r0; out_ema[base + 1] = r1; out_ema[base + 2] = r2; out_ema[base + 3] = r3;
    out_emb[base + 0] = r0 / ncs; out_emb[base + 1] = r1 / ncs;
    out_emb[base + 2] = r2 / ncs; out_emb[base + 3] = r3 / ncs;
    if (blockIdx.x == 0 && threadIdx.x == 0) {
        float m = scal[0] * (1.0f / 2097152.0f);
        out_loss[0] = m + 0.25f * m;
    }
}

extern "C" void kernel_launch(void* const* d_in, const int* in_sizes, int n_in,
                              void* d_out, int out_size, void* d_ws, size_t ws_size,
                              hipStream_t stream) {
    const float* z   = (const float*)d_in[0];
    const float* emb = (const float*)d_in[1];
    const float* cs  = (const float*)d_in[2];
    const float* ema = (const float*)d_in[3];
    float* out = (float*)d_out;
    float* wsf = (float*)d_ws;

    float* asq  = wsf + OFF_ASQ;
    float* bsq  = wsf + OFF_BSQ;
    int*   idxw = (int*)(wsf + OFF_IDX);
    float* ncs0 = wsf + OFF_NCS0;
    int*   cnt  = (int*)(wsf + OFF_CNT);
    float* scal = wsf + OFF_SCAL;
    float* dw   = wsf + OFF_DW;
    _Float16* Bh = (_Float16*)(wsf + OFF_BH);
    _Float16* Bm = (_Float16*)(wsf + OFF_BM);

    float* out_zq   = out;                 // [2097152]
    float* out_loss = out + 2097152;       // [1]
    float* out_idx  = out + 2097153;       // [8192]
    float* out_ncs  = out + 2105345;       // [8192]
    float* out_ema  = out + 2113537;       // [2097152]
    float* out_emb  = out + 4210689;       // [2097152]

    // A fp16 matrices live in the (dead until k_fin) out_ema region, 16B-aligned
    _Float16* Ah = (_Float16*)(out + 2113540);             // 4 MB
    _Float16* Am = (_Float16*)(out + 2113540 + 1048576);   // 4 MB (tail 3 floats into out_emb region, dead until k_fin)
    // pdk partials live in the (dead until k_zq) out_zq region: [8192][128] u64 = 8 MB exact
    unsigned long long* pdk = (unsigned long long*)out;

    // zero cnt + scal + dw in one shot
    hipMemsetAsync(wsf + OFF_CNT, 0, (size_t)(OFF_DW + 2097152 - OFF_CNT) * sizeof(float), stream);

    k_sqz<<<32, 256, 0, stream>>>(z, asq);
    prep_e<<<2048, 256, 0, stream>>>(emb, bsq, Bh, Bm);
    prep_z<<<512, 256, 0, stream>>>(z, Ah, Am);
    k_main<<<dim3(64, 64), 256, 0, stream>>>(Ah, Am, Bh, Bm, asq, bsq, pdk);
    k_red<<<2048, 256, 0, stream>>>(pdk, idxw, out_idx, cnt);
    k_zq<<<dim3(128, 4), 256, 0, stream>>>(z, emb, idxw, out_zq, dw, scal);
    k_ncs<<<32, 256, 0, stream>>>(cs, cnt, ncs0, scal);
    k_fin<<<2048, 256, 0, stream>>>(ncs0, ema, dw, scal, out_ncs, out_ema, out_emb, out_loss);
}

// Round 3
// 370.635 us; speedup vs baseline: 1.6581x; 1.0399x over previous
//
#include <hip/hip_runtime.h>

#define CHW 262144   // C*H*W = 256*32*32
#define HWD 1024     // H*W

typedef _Float16 v8h __attribute__((ext_vector_type(8)));
typedef _Float16 v4h __attribute__((ext_vector_type(4)));
typedef float    v4f __attribute__((ext_vector_type(4)));

// workspace layout (float offsets)
static const unsigned OFF_ASQ  = 0;        // ||z_n||^2 [8192]
static const unsigned OFF_BSQ  = 8192;     // ||e_k||^2 [8192]
static const unsigned OFF_IDX  = 16384;    // idx (int) [8192]
static const unsigned OFF_NCS0 = 24576;    // pre-norm new_cs [8192]
static const unsigned OFF_CNT  = 32768;    // counts (int, ZEROED) [8192]
static const unsigned OFF_SCAL = 40960;    // [0]=loss_sum [1]=n_sum (ZEROED)
static const unsigned OFF_DW   = 49152;    // dw (ZEROED) [2097152]
static const unsigned OFF_BH   = 2146304;  // Bh fp16 [8192*256] (1048576 floats)
static const unsigned OFF_BM   = 3194880;  // Bm fp16 [8192*256]
// end: 4243456 floats = 17.0 MB

#define GLL(g, l) __builtin_amdgcn_global_load_lds( \
    (const __attribute__((address_space(1))) void*)(g), \
    (__attribute__((address_space(3))) void*)(l), 16, 0, 0)

// ---- ||z_n||^2 (sequential c-chain: order must stay fixed across rounds) ----
__global__ __launch_bounds__(256) void k_sqz(const float* __restrict__ z, float* __restrict__ asq) {
    int n = blockIdx.x * 256 + threadIdx.x;
    const float* p = z + (size_t)(n >> 10) * CHW + (n & 1023);
    float s = 0.f;
    #pragma unroll 8
    for (int c = 0; c < 256; ++c) { float v = p[(size_t)c << 10]; s = fmaf(v, v, s); }
    asq[n] = s;
}

// ---- emb -> bsq + fp16 split (e' = e*2^13; m-part scaled by 2^11) ----
__global__ __launch_bounds__(256) void prep_e(const float* __restrict__ emb, float* __restrict__ bsq,
        _Float16* __restrict__ Bh, _Float16* __restrict__ Bm) {
    int w = blockIdx.x * 4 + (threadIdx.x >> 6);
    int lane = threadIdx.x & 63;
    float4 v = *(const float4*)(emb + (size_t)w * 256 + lane * 4);
    float s = v.x * v.x;
    s = fmaf(v.y, v.y, s); s = fmaf(v.z, v.z, s); s = fmaf(v.w, v.w, s);
    #pragma unroll
    for (int m = 1; m < 64; m <<= 1) s += __shfl_xor(s, m, 64);
    if (lane == 0) bsq[w] = s;
    float e0 = v.x * 8192.0f, e1 = v.y * 8192.0f, e2 = v.z * 8192.0f, e3 = v.w * 8192.0f;
    _Float16 h0 = (_Float16)e0, h1 = (_Float16)e1, h2 = (_Float16)e2, h3 = (_Float16)e3;
    v4h hv = {h0, h1, h2, h3};
    v4h mv = {(_Float16)((e0 - (float)h0) * 2048.0f),
              (_Float16)((e1 - (float)h1) * 2048.0f),
              (_Float16)((e2 - (float)h2) * 2048.0f),
              (_Float16)((e3 - (float)h3) * 2048.0f)};
    *(v4h*)(Bh + (size_t)w * 256 + lane * 4) = hv;
    *(v4h*)(Bm + (size_t)w * 256 + lane * 4) = mv;
}

// ---- z [b][c][hw] -> Ah/Am [n][c] fp16 (transpose + split) ----
__global__ __launch_bounds__(256) void prep_z(const float* __restrict__ z,
        _Float16* __restrict__ Ah, _Float16* __restrict__ Am) {
    __shared__ float s[64][65];
    int hw0 = (blockIdx.x & 15) * 64;
    int c0  = ((blockIdx.x >> 4) & 3) * 64;
    int b   = blockIdx.x >> 6;
    int t = threadIdx.x;
    #pragma unroll
    for (int ii = 0; ii < 16; ++ii) {
        int e = t + ii * 256;
        int c = e >> 6, x = e & 63;
        s[c][x] = z[(size_t)b * CHW + (size_t)(c0 + c) * HWD + hw0 + x];
    }
    __syncthreads();
    int n = t & 63, cseg = (t >> 6) * 16;
    _Float16 hbuf[16], mbuf[16];
    #pragma unroll
    for (int j = 0; j < 16; ++j) {
        float v = s[cseg + j][n];
        _Float16 h = (_Float16)v;
        float r = v - (float)h;
        hbuf[j] = h;
        mbuf[j] = (_Float16)(r * 2048.0f);
    }
    size_t off = ((size_t)b * 1024 + hw0 + n) * 256 + c0 + cseg;
    *(v8h*)(Ah + off)     = *(v8h*)(hbuf);
    *(v8h*)(Ah + off + 8) = *(v8h*)(hbuf + 8);
    *(v8h*)(Am + off)     = *(v8h*)(mbuf);
    *(v8h*)(Am + off + 8) = *(v8h*)(mbuf + 8);
}

// ---- main: 128x128 MFMA tiles, double-buffered LDS, post-barrier prefetch ----
__global__ __launch_bounds__(256, 2) void k_main(
        const _Float16* __restrict__ Ah, const _Float16* __restrict__ Am,
        const _Float16* __restrict__ Bh, const _Float16* __restrict__ Bm,
        const float* __restrict__ asq, const float* __restrict__ bsq,
        unsigned long long* __restrict__ pdk) {
    __shared__ _Float16 lds[32768];  // 64 KB: 2 buffers x (4 mats x [128 rows x 32 halves]), XOR-swizzled
    const int kt = blockIdx.x, nt = blockIdx.y;
    const int n0 = nt * 128, k0 = kt * 128;
    const int t = threadIdx.x;
    const int lane = t & 63, w = t >> 6;
    const int wrow = w >> 1, wcol = w & 1;
    const int lm = lane & 15, quad = lane >> 4;

    v4f acc1[4][4], acc2[4][4];
    #pragma unroll
    for (int i = 0; i < 4; ++i)
        #pragma unroll
        for (int j = 0; j < 4; ++j) { acc1[i][j] = (v4f){0.f,0.f,0.f,0.f}; acc2[i][j] = (v4f){0.f,0.f,0.f,0.f}; }

    // staging: chunk = q*256 + t; row = chunk>>2; c4 = (chunk&3) ^ ((row>>1)&3)
    const int row0 = t >> 2;
    const int c40 = (t & 3) ^ ((row0 >> 1) & 3);
    const char* gA0  = (const char*)Ah + (size_t)(n0 + row0) * 512 + c40 * 16;
    const char* gAm0 = (const char*)Am + (size_t)(n0 + row0) * 512 + c40 * 16;
    const char* gB0  = (const char*)Bh + (size_t)(k0 + row0) * 512 + c40 * 16;
    const char* gBm0 = (const char*)Bm + (size_t)(k0 + row0) * 512 + c40 * 16;

    // frag LDS half-offsets (within one 16384-half buffer)
    int sa[4], sb[4];
    #pragma unroll
    for (int i = 0; i < 4; ++i) {
        int mr = wrow * 64 + i * 16 + lm;
        sa[i] = mr * 32 + ((quad ^ ((mr >> 1) & 3)) * 8);
        int nr = wcol * 64 + i * 16 + lm;
        sb[i] = nr * 32 + ((quad ^ ((nr >> 1) & 3)) * 8);
    }

    auto stage = [&](int cb, int buf) {
        const size_t co = (size_t)cb * 64;  // 32 c * 2B
        _Float16* l0 = lds + buf * 16384 + t * 8;   // q=0 dest (per-lane 16B)
        _Float16* l1 = l0 + 2048;                   // q=1 dest
        GLL(gA0 + co,           l0);
        GLL(gA0 + co + 32768,   l1);                // +64 rows * 512 B
        GLL(gAm0 + co,          l0 + 4096);
        GLL(gAm0 + co + 32768,  l1 + 4096);
        GLL(gB0 + co,           l0 + 8192);
        GLL(gB0 + co + 32768,   l1 + 8192);
        GLL(gBm0 + co,          l0 + 12288);
        GLL(gBm0 + co + 32768,  l1 + 12288);
    };

    stage(0, 0);
    for (int cb = 0; cb < 8; ++cb) {
        __syncthreads();                       // drains stage(cb) (issued a full compute phase ago)
        if (cb < 7) stage(cb + 1, (cb + 1) & 1);   // prefetch into other buffer, post-barrier
        const _Float16* L = lds + (cb & 1) * 16384;

        v8h fa[4], fam[4], fb[4], fbm[4];
        #pragma unroll
        for (int i = 0; i < 4; ++i) {
            fa[i]  = *(const v8h*)(L + sa[i]);
            fam[i] = *(const v8h*)(L + 4096 + sa[i]);
            fb[i]  = *(const v8h*)(L + 8192 + sb[i]);
            fbm[i] = *(const v8h*)(L + 12288 + sb[i]);
        }
        #pragma unroll
        for (int i = 0; i < 4; ++i)
            #pragma unroll
            for (int j = 0; j < 4; ++j) {
                acc1[i][j] = __builtin_amdgcn_mfma_f32_16x16x32_f16(fa[i], fb[j], acc1[i][j], 0, 0, 0);
                acc2[i][j] = __builtin_amdgcn_mfma_f32_16x16x32_f16(fa[i], fbm[j], acc2[i][j], 0, 0, 0);
                acc2[i][j] = __builtin_amdgcn_mfma_f32_16x16x32_f16(fam[i], fb[j], acc2[i][j], 0, 0, 0);
            }
    }

    // epilogue: d = fl(fl(a+b) - 2*S), S = (acc1 + acc2*2^-11)*2^-13
    float bvv[4];
    #pragma unroll
    for (int j = 0; j < 4; ++j) bvv[j] = bsq[k0 + wcol * 64 + j * 16 + lm];
    #pragma unroll
    for (int i = 0; i < 4; ++i) {
        #pragma unroll
        for (int r = 0; r < 4; ++r) {
            int m = n0 + wrow * 64 + i * 16 + quad * 4 + r;
            float av_ = asq[m];
            unsigned long long best = ~0ull;
            #pragma unroll
            for (int j = 0; j < 4; ++j) {
                float S = fmaf(acc2[i][j][r], 4.8828125e-4f, acc1[i][j][r]) * 1.220703125e-4f;
                float dd = (av_ + bvv[j]) - 2.0f * S;
                int col = k0 + wcol * 64 + j * 16 + lm;
                unsigned long long key = ((unsigned long long)__float_as_uint(dd) << 13) | (unsigned)col;
                best = key < best ? key : best;
            }
            #pragma unroll
            for (int xm = 1; xm < 16; xm <<= 1) {
                unsigned long long o = __shfl_xor(best, xm, 64);
                best = o < best ? o : best;
            }
            if (lm == 0) pdk[(size_t)m * 128 + kt * 2 + wcol] = best;
        }
    }
}

// ---- reduce 128 tile-partials per n, write idx, histogram ----
__global__ __launch_bounds__(256) void k_red(const unsigned long long* __restrict__ pdk,
        int* __restrict__ idxw, float* __restrict__ out_idx, int* __restrict__ cnt) {
    int n = blockIdx.x * 4 + (threadIdx.x >> 6);
    int lane = threadIdx.x & 63;
    unsigned long long a = pdk[(size_t)n * 128 + lane];
    unsigned long long b = pdk[(size_t)n * 128 + 64 + lane];
    unsigned long long v = a < b ? a : b;
    #pragma unroll
    for (int m = 1; m < 64; m <<= 1) {
        unsigned long long o = __shfl_xor(v, m, 64);
        v = o < v ? o : v;
    }
    if (lane == 0) {
        int k = (int)(v & 8191u);
        idxw[n] = k;
        out_idx[n] = (float)k;
        atomicAdd(cnt + k, 1);
    }
}

// ---- z_q gather + straight-through write + loss partial + dw scatter ----
__global__ __launch_bounds__(256) void k_zq(const float* __restrict__ z, const float* __restrict__ emb,
        const int* __restrict__ idxw, float* __restrict__ out_zq,
        float* __restrict__ dw, float* __restrict__ scal) {
    int n0 = blockIdx.x * 64, c00 = blockIdx.y * 64;
    int lane = threadIdx.x & 63, g = threadIdx.x >> 6;
    int n = n0 + lane;
    int b = n >> 10, hw = n & 1023;
    int idxn = idxw[n];
    const float* zr = z + (size_t)b * CHW + hw;
    const float* er = emb + (size_t)idxn * 256;
    float* dwr = dw + (size_t)idxn * 256;
    float* oz = out_zq + (size_t)b * CHW + hw;
    float ls = 0.f;
    #pragma unroll
    for (int q = 0; q < 4; ++q) {
        int c = c00 + g * 16 + q * 4;
        float4 e4 = *(const float4*)(er + c);   // vectorized gather (row 16B-aligned)
        float ev[4] = {e4.x, e4.y, e4.z, e4.w};
        #pragma unroll
        for (int r = 0; r < 4; ++r) {
            float zp = zr[(size_t)(c + r) << 10];
            float dif = ev[r] - zp;
            oz[(size_t)(c + r) << 10] = zp + dif;
            ls = fmaf(dif, dif, ls);
            atomicAdd(dwr + c + r, zp);
        }
    }
    #pragma unroll
    for (int m = 1; m < 64; m <<= 1) ls += __shfl_xor(ls, m, 64);
    __shared__ float red[4];
    if (lane == 0) red[g] = ls;
    __syncthreads();
    if (threadIdx.x == 0) atomicAdd(scal, red[0] + red[1] + red[2] + red[3]);
}

// ---- new_cs pre-normalization + n = sum ----
__global__ __launch_bounds__(256) void k_ncs(const float* __restrict__ cs, const int* __restrict__ cnt,
        float* __restrict__ ncs0, float* __restrict__ scal) {
    int k = blockIdx.x * 256 + threadIdx.x;
    const float C1 = (float)(1.0 - 0.99);
    float v = cs[k] * 0.99f + C1 * (float)cnt[k];
    ncs0[k] = v;
    float s = v;
    #pragma unroll
    for (int m = 1; m < 64; m <<= 1) s += __shfl_xor(s, m, 64);
    __shared__ float red[4];
    if ((threadIdx.x & 63) == 0) red[threadIdx.x >> 6] = s;
    __syncthreads();
    if (threadIdx.x == 0) atomicAdd(scal + 1, red[0] + red[1] + red[2] + red[3]);
}

// ---- finalize ----
__global__ __launch_bounds__(256) void k_fin(const float* __restrict__ ncs0, const float* __restrict__ ema,
        const float* __restrict__ dw, const float* __restrict__ scal,
        float* __restrict__ out_ncs, float* __restrict__ out_ema,
        float* __restrict__ out_emb, float* __restrict__ out_loss) {
    int k = blockIdx.x * 4 + (threadIdx.x >> 6);
    int lane = threadIdx.x & 63;
    float nsum = scal[1];
    const float KEPS = (float)(8192 * 1e-5);
    float ncs = (ncs0[k] + 1e-5f) / (nsum + KEPS) * nsum;
    if (lane == 0) out_ncs[k] = ncs;
    const float C1 = (float)(1.0 - 0.99);
    size_t base = (size_t)k * 256 + lane * 4;
    float4 e4 = *(const float4*)(ema + base);
    float4 d4 = *(const float4*)(dw + base);
    float r0 = e4.x * 0.99f + C1 * d4.x;
    float r1 = e4.y * 0.99f + C1 * d4.y;
    float r2 = e4.z * 0.99f + C1 * d4.z;
    float r3 = e4.w * 0.99f + C1 * d4.w;
    out_ema[base + 0] = r0; out_ema[base + 1] = r1; out_ema[base + 2] = r2; out_ema[base + 3] = r3;
    out_emb[base + 0] = r0 / ncs; out_emb[base + 1] = r1 / ncs;
    out_emb[base + 2] = r2 / ncs; out_emb[base + 3] = r3 / ncs;
    if (blockIdx.x == 0 && threadIdx.x == 0) {
        float m = scal[0] * (1.0f / 2097152.0f);
        out_loss[0] = m + 0.25f * m;
    }
}

extern "C" void kernel_launch(void* const* d_in, const int* in_sizes, int n_in,
                              void* d_out, int out_size, void* d_ws, size_t ws_size,
                              hipStream_t stream) {
    const float* z   = (const float*)d_in[0];
    const float* emb = (const float*)d_in[1];
    const float* cs  = (const float*)d_in[2];
    const float* ema = (const float*)d_in[3];
    float* out = (float*)d_out;
    float* wsf = (float*)d_ws;

    float* asq  = wsf + OFF_ASQ;
    float* bsq  = wsf + OFF_BSQ;
    int*   idxw = (int*)(wsf + OFF_IDX);
    float* ncs0 = wsf + OFF_NCS0;
    int*   cnt  = (int*)(wsf + OFF_CNT);
    float* scal = wsf + OFF_SCAL;
    float* dw   = wsf + OFF_DW;
    _Float16* Bh = (_Float16*)(wsf + OFF_BH);
    _Float16* Bm = (_Float16*)(wsf + OFF_BM);

    float* out_zq   = out;                 // [2097152]
    float* out_loss = out + 2097152;       // [1]
    float* out_idx  = out + 2097153;       // [8192]
    float* out_ncs  = out + 2105345;       // [8192]
    float* out_ema  = out + 2113537;       // [2097152]
    float* out_emb  = out + 4210689;       // [2097152]

    // A fp16 matrices live in the (dead until k_fin) out_ema region, 16B-aligned
    _Float16* Ah = (_Float16*)(out + 2113540);             // 4 MB
    _Float16* Am = (_Float16*)(out + 2113540 + 1048576);   // 4 MB (tail spills into out_emb region, dead until k_fin)
    // pdk partials live in the (dead until k_zq) out_zq region: [8192][128] u64 = 8 MB exact
    unsigned long long* pdk = (unsigned long long*)out;

    // zero cnt + scal + dw in one shot
    hipMemsetAsync(wsf + OFF_CNT, 0, (size_t)(OFF_DW + 2097152 - OFF_CNT) * sizeof(float), stream);

    k_sqz<<<32, 256, 0, stream>>>(z, asq);
    prep_e<<<2048, 256, 0, stream>>>(emb, bsq, Bh, Bm);
    prep_z<<<512, 256, 0, stream>>>(z, Ah, Am);
    k_main<<<dim3(64, 64), 256, 0, stream>>>(Ah, Am, Bh, Bm, asq, bsq, pdk);
    k_red<<<2048, 256, 0, stream>>>(pdk, idxw, out_idx, cnt);
    k_zq<<<dim3(128, 4), 256, 0, stream>>>(z, emb, idxw, out_zq, dw, scal);
    k_ncs<<<32, 256, 0, stream>>>(cs, cnt, ncs0, scal);
    k_fin<<<2048, 256, 0, stream>>>(ncs0, ema, dw, scal, out_ncs, out_ema, out_emb, out_loss);
}